// Round 1
// baseline (73.107 us; speedup 1.0000x reference)
//
#include <hip/hip_runtime.h>
#include <hip/hip_bf16.h>

#define SPATIAL_SCALE 0.0625f
#define POOLED 7
#define PARTS 7
#define SAMPLES 4
#define TRANS_STD 0.1f

// B, C, H, W fixed by the reference setup
#define BB 2
#define CC 128
#define HH 128
#define WW 128

// ---------------- transpose (B,C,H,W) -> (B,H,W,C) ----------------
// Treat per-batch as 2D transpose of (C, HW): out[p][c] = in[c][p].
__global__ void transpose_chw_hwc(const float* __restrict__ in,
                                  float* __restrict__ out) {
    __shared__ float tile[32][33];
    const int HW = HH * WW;
    int b  = blockIdx.z;
    size_t base = (size_t)b * CC * HW;
    int p0 = blockIdx.x * 32;   // position (y*W+x) tile origin
    int c0 = blockIdx.y * 32;   // channel tile origin
    int tx = threadIdx.x;       // 0..31
    int ty = threadIdx.y;       // 0..7
    #pragma unroll
    for (int i = ty; i < 32; i += 8) {
        tile[i][tx] = in[base + (size_t)(c0 + i) * HW + (p0 + tx)];
    }
    __syncthreads();
    #pragma unroll
    for (int i = ty; i < 32; i += 8) {
        out[base + (size_t)(p0 + i) * CC + (c0 + tx)] = tile[tx][i];
    }
}

// ---------------- deformable PS-ROI pooling ----------------
// One block per (n, ph, pw). 128 threads = channels.
// CHLAST: feature layout (B,H,W,C) (transposed, coalesced); else (B,C,H,W).
template <bool CHLAST>
__global__ void dpsroi_pool(const float* __restrict__ feat,
                            const float* __restrict__ rois,
                            const float* __restrict__ offset,
                            float* __restrict__ out,
                            int N) {
    int bin = blockIdx.x;
    int pw = bin % POOLED;
    int ph = (bin / POOLED) % POOLED;
    int n  = bin / (POOLED * POOLED);
    int c  = threadIdx.x;

    // ROI geometry (uniform across block; every thread computes it — cheap)
    float r0 = rois[n * 5 + 0];
    float r1 = rois[n * 5 + 1];
    float r2 = rois[n * 5 + 2];
    float r3 = rois[n * 5 + 3];
    float r4 = rois[n * 5 + 4];
    int  b      = (int)r0;
    float roi_sw = rintf(r1) * SPATIAL_SCALE - 0.5f;
    float roi_sh = rintf(r2) * SPATIAL_SCALE - 0.5f;
    float roi_ew = rintf(r3 + 1.0f) * SPATIAL_SCALE - 0.5f;
    float roi_eh = rintf(r4 + 1.0f) * SPATIAL_SCALE - 0.5f;
    float roi_w = fmaxf(roi_ew - roi_sw, 0.1f);
    float roi_h = fmaxf(roi_eh - roi_sh, 0.1f);
    float bin_w = roi_w * (1.0f / POOLED);
    float bin_h = roi_h * (1.0f / POOLED);
    float sub_w = bin_w * (1.0f / SAMPLES);
    float sub_h = bin_h * (1.0f / SAMPLES);

    // part[p] == p since POOLED == PARTS
    float tx = offset[((n * 2 + 0) * PARTS + ph) * PARTS + pw] * TRANS_STD;
    float ty = offset[((n * 2 + 1) * PARTS + ph) * PARTS + pw] * TRANS_STD;

    float wstart = (float)pw * bin_w + roi_sw + tx * roi_w;
    float hstart = (float)ph * bin_h + roi_sh + ty * roi_h;

    const float* fb;
    if (CHLAST) {
        fb = feat + (size_t)b * HH * WW * CC;
    } else {
        fb = feat + ((size_t)b * CC + c) * HH * WW;
    }

    float s = 0.0f;
    int cnt = 0;
    #pragma unroll
    for (int iy = 0; iy < SAMPLES; ++iy) {
        float h = hstart + (float)iy * sub_h;
        #pragma unroll
        for (int ix = 0; ix < SAMPLES; ++ix) {
            float w = wstart + (float)ix * sub_w;
            bool m = (w >= -0.5f) & (w <= (float)WW - 0.5f) &
                     (h >= -0.5f) & (h <= (float)HH - 0.5f);
            if (!m) continue;          // uniform across the block
            float wc = fminf(fmaxf(w, 0.0f), (float)WW - 1.0f);
            float hc = fminf(fmaxf(h, 0.0f), (float)HH - 1.0f);
            float x0f = floorf(wc);
            float y0f = floorf(hc);
            int x0 = (int)x0f;
            int y0 = (int)y0f;
            int x1 = (int)ceilf(wc);
            int y1 = (int)ceilf(hc);
            float dx = wc - x0f;
            float dy = hc - y0f;
            float v00, v01, v10, v11;
            if (CHLAST) {
                v00 = fb[((size_t)y0 * WW + x0) * CC + c];
                v01 = fb[((size_t)y0 * WW + x1) * CC + c];
                v10 = fb[((size_t)y1 * WW + x0) * CC + c];
                v11 = fb[((size_t)y1 * WW + x1) * CC + c];
            } else {
                v00 = fb[(size_t)y0 * WW + x0];
                v01 = fb[(size_t)y0 * WW + x1];
                v10 = fb[(size_t)y1 * WW + x0];
                v11 = fb[(size_t)y1 * WW + x1];
            }
            s += (1.0f - dx) * (1.0f - dy) * v00 + dx * (1.0f - dy) * v01 +
                 (1.0f - dx) * dy * v10 + dx * dy * v11;
            cnt++;
        }
    }
    float o = (cnt > 0) ? s / (float)cnt : 0.0f;
    // output layout (N, C, POOLED, POOLED)
    out[(((size_t)n * CC + c) * POOLED + ph) * POOLED + pw] = o;
}

extern "C" void kernel_launch(void* const* d_in, const int* in_sizes, int n_in,
                              void* d_out, int out_size, void* d_ws, size_t ws_size,
                              hipStream_t stream) {
    const float* data   = (const float*)d_in[0];
    const float* rois   = (const float*)d_in[1];
    const float* offset = (const float*)d_in[2];
    float* out = (float*)d_out;
    int N = in_sizes[1] / 5;

    size_t feat_bytes = (size_t)BB * CC * HH * WW * sizeof(float);
    int nbins = N * POOLED * POOLED;

    if (ws_size >= feat_bytes) {
        float* featT = (float*)d_ws;
        // (B,C,H,W) -> (B,H,W,C)
        dim3 tgrid(HH * WW / 32, CC / 32, BB);
        dim3 tblk(32, 8);
        hipLaunchKernelGGL(transpose_chw_hwc, tgrid, tblk, 0, stream, data, featT);
        hipLaunchKernelGGL((dpsroi_pool<true>), dim3(nbins), dim3(CC), 0, stream,
                           featT, rois, offset, out, N);
    } else {
        hipLaunchKernelGGL((dpsroi_pool<false>), dim3(nbins), dim3(CC), 0, stream,
                           data, rois, offset, out, N);
    }
}

// Round 2
// 58.366 us; speedup vs baseline: 1.2526x; 1.2526x over previous
//
#include <hip/hip_runtime.h>
#include <hip/hip_bf16.h>

#define SPATIAL_SCALE 0.0625f
#define POOLED 7
#define PARTS 7
#define SAMPLES 4
#define NSAMP (SAMPLES * SAMPLES)
#define TRANS_STD 0.1f

#define BB 2
#define CC 128
#define HH 128
#define WW 128

// ---------------- transpose (B,C,H,W) -> (B,H,W,C) ----------------
__global__ void transpose_chw_hwc(const float* __restrict__ in,
                                  float* __restrict__ out) {
    __shared__ float tile[32][33];
    const int HW = HH * WW;
    int b  = blockIdx.z;
    size_t base = (size_t)b * CC * HW;
    int p0 = blockIdx.x * 32;
    int c0 = blockIdx.y * 32;
    int tx = threadIdx.x;
    int ty = threadIdx.y;
    #pragma unroll
    for (int i = ty; i < 32; i += 8) {
        tile[i][tx] = in[base + (size_t)(c0 + i) * HW + (p0 + tx)];
    }
    __syncthreads();
    #pragma unroll
    for (int i = ty; i < 32; i += 8) {
        out[base + (size_t)(p0 + i) * CC + (c0 + tx)] = tile[tx][i];
    }
}

// ---------------- deformable PS-ROI pooling ----------------
// One block per (n, ph, pw). 128 threads = channels.
// Lanes 0..15 precompute per-sample {4 corner offsets, 4 folded weights}
// into LDS (mask and 1/cnt pre-applied); main loop is pure gather+FMA.
// CHLAST: feat is (B,H,W,C); else (B,C,H,W).
// STAGED: store coalesced to stage buffer (N,bin,C); else direct (N,C,7,7).
template <bool CHLAST, bool STAGED>
__global__ __launch_bounds__(128) void dpsroi_pool2(
        const float* __restrict__ feat,
        const float* __restrict__ rois,
        const float* __restrict__ offset,
        float* __restrict__ outp, int N) {
    __shared__ int4   s_off[NSAMP];
    __shared__ float4 s_wt[NSAMP];

    int bin = blockIdx.x;
    int pw = bin % POOLED;
    int ph = (bin / POOLED) % POOLED;
    int n  = bin / (POOLED * POOLED);
    int tid = threadIdx.x;

    int b = (int)rois[n * 5 + 0];

    if (tid < NSAMP) {
        float r1 = rois[n * 5 + 1];
        float r2 = rois[n * 5 + 2];
        float r3 = rois[n * 5 + 3];
        float r4 = rois[n * 5 + 4];
        float roi_sw = rintf(r1) * SPATIAL_SCALE - 0.5f;
        float roi_sh = rintf(r2) * SPATIAL_SCALE - 0.5f;
        float roi_ew = rintf(r3 + 1.0f) * SPATIAL_SCALE - 0.5f;
        float roi_eh = rintf(r4 + 1.0f) * SPATIAL_SCALE - 0.5f;
        float roi_w = fmaxf(roi_ew - roi_sw, 0.1f);
        float roi_h = fmaxf(roi_eh - roi_sh, 0.1f);
        float bin_w = roi_w * (1.0f / POOLED);
        float bin_h = roi_h * (1.0f / POOLED);
        float sub_w = bin_w * (1.0f / SAMPLES);
        float sub_h = bin_h * (1.0f / SAMPLES);

        float tx = offset[((n * 2 + 0) * PARTS + ph) * PARTS + pw] * TRANS_STD;
        float ty = offset[((n * 2 + 1) * PARTS + ph) * PARTS + pw] * TRANS_STD;

        float wstart = (float)pw * bin_w + roi_sw + tx * roi_w;
        float hstart = (float)ph * bin_h + roi_sh + ty * roi_h;

        int s  = tid;
        int iy = s >> 2;
        int ix = s & 3;
        float h = hstart + (float)iy * sub_h;
        float w = wstart + (float)ix * sub_w;
        bool valid = (w >= -0.5f) & (w <= (float)WW - 0.5f) &
                     (h >= -0.5f) & (h <= (float)HH - 0.5f);
        unsigned long long bal = __ballot(valid);
        int cnt = __builtin_popcountll(bal);
        float sc = 1.0f / (float)(cnt > 0 ? cnt : 1);

        float wc = fminf(fmaxf(w, 0.0f), (float)WW - 1.0f);
        float hc = fminf(fmaxf(h, 0.0f), (float)HH - 1.0f);
        float x0f = floorf(wc);
        float y0f = floorf(hc);
        int x0 = (int)x0f;
        int y0 = (int)y0f;
        int x1 = (int)ceilf(wc);
        int y1 = (int)ceilf(hc);
        float dx = wc - x0f;
        float dy = hc - y0f;

        float m = valid ? sc : 0.0f;
        float w00 = (1.0f - dx) * (1.0f - dy) * m;
        float w01 = dx * (1.0f - dy) * m;
        float w10 = (1.0f - dx) * dy * m;
        float w11 = dx * dy * m;

        int mul = CHLAST ? CC : 1;
        s_off[s] = make_int4((y0 * WW + x0) * mul, (y0 * WW + x1) * mul,
                             (y1 * WW + x0) * mul, (y1 * WW + x1) * mul);
        s_wt[s] = make_float4(w00, w01, w10, w11);
    }
    __syncthreads();

    const float* fb;
    if (CHLAST) {
        fb = feat + (size_t)b * HH * WW * CC + tid;   // per-thread channel base
    } else {
        fb = feat + ((size_t)b * CC + tid) * HH * WW;
    }

    float acc = 0.0f;
    #pragma unroll
    for (int s = 0; s < NSAMP; ++s) {
        int4   o = s_off[s];
        float4 wv = s_wt[s];
        acc += wv.x * fb[o.x];
        acc += wv.y * fb[o.y];
        acc += wv.z * fb[o.z];
        acc += wv.w * fb[o.w];
    }

    if (STAGED) {
        // (N, bin, C) coalesced
        outp[(size_t)bin * CC + tid] = acc;
    } else {
        // (N, C, 7, 7) scattered
        outp[(((size_t)n * CC + tid) * POOLED + ph) * POOLED + pw] = acc;
    }
}

// ---------------- relayout (N, bin, C) -> (N, C, bin) ----------------
#define NBIN (POOLED * POOLED)          // 49
#define LPAD 51
__global__ __launch_bounds__(256) void relayout(const float* __restrict__ ws,
                                                float* __restrict__ out) {
    __shared__ float t[CC * LPAD];
    int n = blockIdx.x;
    const float* src = ws + (size_t)n * CC * NBIN;
    for (int i = threadIdx.x; i < CC * NBIN; i += 256) {
        int c = i & (CC - 1);
        int bin = i >> 7;
        t[c * LPAD + bin] = src[i];
    }
    __syncthreads();
    float* dst = out + (size_t)n * CC * NBIN;
    for (int j = threadIdx.x; j < CC * NBIN; j += 256) {
        int c = j / NBIN;
        int bin = j - c * NBIN;
        dst[j] = t[c * LPAD + bin];
    }
}

extern "C" void kernel_launch(void* const* d_in, const int* in_sizes, int n_in,
                              void* d_out, int out_size, void* d_ws, size_t ws_size,
                              hipStream_t stream) {
    const float* data   = (const float*)d_in[0];
    const float* rois   = (const float*)d_in[1];
    const float* offset = (const float*)d_in[2];
    float* out = (float*)d_out;
    int N = in_sizes[1] / 5;

    size_t feat_bytes  = (size_t)BB * CC * HH * WW * sizeof(float);
    size_t stage_bytes = (size_t)N * NBIN * CC * sizeof(float);
    int nbins = N * NBIN;

    if (ws_size >= feat_bytes + stage_bytes) {
        float* featT = (float*)d_ws;
        float* stage = (float*)((char*)d_ws + feat_bytes);
        dim3 tgrid(HH * WW / 32, CC / 32, BB);
        hipLaunchKernelGGL(transpose_chw_hwc, tgrid, dim3(32, 8), 0, stream,
                           data, featT);
        hipLaunchKernelGGL((dpsroi_pool2<true, true>), dim3(nbins), dim3(CC), 0,
                           stream, featT, rois, offset, stage, N);
        hipLaunchKernelGGL(relayout, dim3(N), dim3(256), 0, stream, stage, out);
    } else if (ws_size >= feat_bytes) {
        float* featT = (float*)d_ws;
        dim3 tgrid(HH * WW / 32, CC / 32, BB);
        hipLaunchKernelGGL(transpose_chw_hwc, tgrid, dim3(32, 8), 0, stream,
                           data, featT);
        hipLaunchKernelGGL((dpsroi_pool2<true, false>), dim3(nbins), dim3(CC), 0,
                           stream, featT, rois, offset, out, N);
    } else {
        hipLaunchKernelGGL((dpsroi_pool2<false, false>), dim3(nbins), dim3(CC), 0,
                           stream, data, rois, offset, out, N);
    }
}

// Round 3
// 52.824 us; speedup vs baseline: 1.3840x; 1.1049x over previous
//
#include <hip/hip_runtime.h>
#include <hip/hip_bf16.h>

#define SPATIAL_SCALE 0.0625f
#define POOLED 7
#define NBIN 49
#define PARTS 7
#define SAMPLES 4
#define NSAMP 16
#define TRANS_STD 0.1f

#define BB 2
#define CC 128
#define HH 128
#define WW 128
#define HWC (HH * WW * CC)

#define BPB 8      // bins per block
#define WIN 5      // max window extent (3*sub_w <= 2.91 -> <=5 cells)

// ---------------- transpose (B,C,H,W) -> (B,H,W,C) ----------------
__global__ void transpose_chw_hwc(const float* __restrict__ in,
                                  float* __restrict__ out) {
    __shared__ float tile[32][33];
    const int HW = HH * WW;
    int b  = blockIdx.z;
    size_t base = (size_t)b * CC * HW;
    int p0 = blockIdx.x * 32;
    int c0 = blockIdx.y * 32;
    int tx = threadIdx.x;
    int ty = threadIdx.y;
    #pragma unroll
    for (int i = ty; i < 32; i += 8) {
        tile[i][tx] = in[base + (size_t)(c0 + i) * HW + (p0 + tx)];
    }
    __syncthreads();
    #pragma unroll
    for (int i = ty; i < 32; i += 8) {
        out[base + (size_t)(p0 + i) * CC + (c0 + tx)] = tile[tx][i];
    }
}

// ---------------- dedup deformable PS-ROI pooling ----------------
// Block = 256 threads, BPB bins. Geometry phase: 128 lanes (bin,sample)
// accumulate folded bilinear weights into per-bin 5x5 LDS grids.
// Main phase: 32 lanes/bin, float4 = 4 channels/lane, one weighted load
// per unique window pixel. Output staged coalesced as (bin, C).
__global__ __launch_bounds__(256) void dpsroi_pool3(
        const float* __restrict__ feat,     // (B,H,W,C)
        const float* __restrict__ rois,
        const float* __restrict__ offset,
        float* __restrict__ stage,          // (nbins, C)
        int nbins) {
    __shared__ float s_w[BPB][WIN * WIN];
    __shared__ int4  s_meta[BPB];           // r0, c0, rows, cols
    __shared__ int   s_base[BPB];           // batch element offset

    int tid = threadIdx.x;
    int bin0 = blockIdx.x * BPB;

    for (int i = tid; i < BPB * WIN * WIN; i += 256)
        ((float*)s_w)[i] = 0.0f;
    __syncthreads();

    if (tid < BPB * NSAMP) {
        int bl = tid >> 4;
        int s  = tid & 15;
        int bing = bin0 + bl;
        bool inb = bing < nbins;
        int binc = inb ? bing : 0;
        int pw = binc % POOLED;
        int ph = (binc / POOLED) % POOLED;
        int n  = binc / NBIN;

        float R0 = rois[n * 5 + 0];
        float R1 = rois[n * 5 + 1];
        float R2 = rois[n * 5 + 2];
        float R3 = rois[n * 5 + 3];
        float R4 = rois[n * 5 + 4];
        int b = (int)R0;
        float roi_sw = rintf(R1) * SPATIAL_SCALE - 0.5f;
        float roi_sh = rintf(R2) * SPATIAL_SCALE - 0.5f;
        float roi_ew = rintf(R3 + 1.0f) * SPATIAL_SCALE - 0.5f;
        float roi_eh = rintf(R4 + 1.0f) * SPATIAL_SCALE - 0.5f;
        float roi_w = fmaxf(roi_ew - roi_sw, 0.1f);
        float roi_h = fmaxf(roi_eh - roi_sh, 0.1f);
        float bin_w = roi_w * (1.0f / POOLED);
        float bin_h = roi_h * (1.0f / POOLED);
        float sub_w = bin_w * (1.0f / SAMPLES);
        float sub_h = bin_h * (1.0f / SAMPLES);

        float tx = offset[((n * 2 + 0) * PARTS + ph) * PARTS + pw] * TRANS_STD;
        float ty = offset[((n * 2 + 1) * PARTS + ph) * PARTS + pw] * TRANS_STD;
        float wstart = (float)pw * bin_w + roi_sw + tx * roi_w;
        float hstart = (float)ph * bin_h + roi_sh + ty * roi_h;

        int iy = s >> 2;
        int ix = s & 3;
        float h = hstart + (float)iy * sub_h;
        float w = wstart + (float)ix * sub_w;
        bool valid = inb & (w >= -0.5f) & (w <= (float)WW - 0.5f) &
                           (h >= -0.5f) & (h <= (float)HH - 0.5f);
        unsigned long long bal = __ballot(valid);
        int g = (tid >> 4) & 3;   // sample-group within this wave
        int cnt = __builtin_popcountll((bal >> (g * 16)) & 0xFFFFull);
        float sc = (cnt > 0) ? 1.0f / (float)cnt : 0.0f;

        // window bounds: w,h monotone in ix,iy (sub_w,sub_h > 0), same FP exprs
        float wlo = fminf(fmaxf(wstart, 0.0f), (float)WW - 1.0f);
        float whi = fminf(fmaxf(wstart + 3.0f * sub_w, 0.0f), (float)WW - 1.0f);
        float hlo = fminf(fmaxf(hstart, 0.0f), (float)HH - 1.0f);
        float hhi = fminf(fmaxf(hstart + 3.0f * sub_h, 0.0f), (float)HH - 1.0f);
        int c0 = (int)floorf(wlo);
        int c1 = (int)ceilf(whi);
        int r0 = (int)floorf(hlo);
        int r1 = (int)ceilf(hhi);

        if (valid) {
            float wc = fminf(fmaxf(w, 0.0f), (float)WW - 1.0f);
            float hc = fminf(fmaxf(h, 0.0f), (float)HH - 1.0f);
            float x0f = floorf(wc);
            float y0f = floorf(hc);
            int x0 = (int)x0f - c0;
            int y0 = (int)y0f - r0;
            int x1 = (int)ceilf(wc) - c0;
            int y1 = (int)ceilf(hc) - r0;
            float dx = wc - x0f;
            float dy = hc - y0f;
            atomicAdd(&s_w[bl][y0 * WIN + x0], (1.0f - dx) * (1.0f - dy) * sc);
            atomicAdd(&s_w[bl][y0 * WIN + x1], dx * (1.0f - dy) * sc);
            atomicAdd(&s_w[bl][y1 * WIN + x0], (1.0f - dx) * dy * sc);
            atomicAdd(&s_w[bl][y1 * WIN + x1], dx * dy * sc);
        }
        if (inb && s == 0) {
            s_meta[bl] = make_int4(r0, c0, r1 - r0 + 1, c1 - c0 + 1);
            s_base[bl] = b * HWC;
        }
    }
    __syncthreads();

    // main gather: 32 lanes per bin, 4 channels per lane
    int bl  = tid >> 5;
    int l32 = tid & 31;
    int bing = bin0 + bl;
    if (bing < nbins) {
        int4 m = s_meta[bl];
        const float* fb = feat + s_base[bl] + l32 * 4;
        float4 acc = make_float4(0.0f, 0.0f, 0.0f, 0.0f);
        int rowoff = (m.x * WW + m.y) * CC;
        for (int r = 0; r < m.z; ++r) {
            int off = rowoff;
            #pragma unroll 1
            for (int c = 0; c < m.w; ++c) {
                float wg = s_w[bl][r * WIN + c];
                if (wg != 0.0f) {
                    float4 v = *(const float4*)(fb + off);
                    acc.x += wg * v.x;
                    acc.y += wg * v.y;
                    acc.z += wg * v.z;
                    acc.w += wg * v.w;
                }
                off += CC;
            }
            rowoff += WW * CC;
        }
        *(float4*)(stage + (size_t)bing * CC + l32 * 4) = acc;
    }
}

// ---------------- relayout (N, bin, C) -> (N, C, bin) ----------------
#define LPAD 51
__global__ __launch_bounds__(256) void relayout(const float* __restrict__ ws,
                                                float* __restrict__ out) {
    __shared__ float t[CC * LPAD];
    int n = blockIdx.x;
    const float* src = ws + (size_t)n * CC * NBIN;
    for (int i = threadIdx.x; i < CC * NBIN; i += 256) {
        int c = i & (CC - 1);
        int bin = i >> 7;
        t[c * LPAD + bin] = src[i];
    }
    __syncthreads();
    float* dst = out + (size_t)n * CC * NBIN;
    for (int j = threadIdx.x; j < CC * NBIN; j += 256) {
        int c = j / NBIN;
        int bin = j - c * NBIN;
        dst[j] = t[c * LPAD + bin];
    }
}

// ---------------- fallback (no workspace): direct CHW ----------------
__global__ __launch_bounds__(128) void dpsroi_fallback(
        const float* __restrict__ feat,
        const float* __restrict__ rois,
        const float* __restrict__ offset,
        float* __restrict__ out, int N) {
    int bin = blockIdx.x;
    int pw = bin % POOLED;
    int ph = (bin / POOLED) % POOLED;
    int n  = bin / NBIN;
    int c  = threadIdx.x;
    float R1 = rois[n * 5 + 1], R2 = rois[n * 5 + 2];
    float R3 = rois[n * 5 + 3], R4 = rois[n * 5 + 4];
    int b = (int)rois[n * 5 + 0];
    float roi_sw = rintf(R1) * SPATIAL_SCALE - 0.5f;
    float roi_sh = rintf(R2) * SPATIAL_SCALE - 0.5f;
    float roi_ew = rintf(R3 + 1.0f) * SPATIAL_SCALE - 0.5f;
    float roi_eh = rintf(R4 + 1.0f) * SPATIAL_SCALE - 0.5f;
    float roi_w = fmaxf(roi_ew - roi_sw, 0.1f);
    float roi_h = fmaxf(roi_eh - roi_sh, 0.1f);
    float bin_w = roi_w / POOLED, bin_h = roi_h / POOLED;
    float sub_w = bin_w / SAMPLES, sub_h = bin_h / SAMPLES;
    float tx = offset[((n * 2 + 0) * PARTS + ph) * PARTS + pw] * TRANS_STD;
    float ty = offset[((n * 2 + 1) * PARTS + ph) * PARTS + pw] * TRANS_STD;
    float wstart = (float)pw * bin_w + roi_sw + tx * roi_w;
    float hstart = (float)ph * bin_h + roi_sh + ty * roi_h;
    const float* fb = feat + ((size_t)b * CC + c) * HH * WW;
    float s = 0.0f; int cnt = 0;
    for (int iy = 0; iy < SAMPLES; ++iy) {
        float h = hstart + iy * sub_h;
        for (int ix = 0; ix < SAMPLES; ++ix) {
            float w = wstart + ix * sub_w;
            if (!((w >= -0.5f) & (w <= WW - 0.5f) & (h >= -0.5f) & (h <= HH - 0.5f)))
                continue;
            float wc = fminf(fmaxf(w, 0.0f), WW - 1.0f);
            float hc = fminf(fmaxf(h, 0.0f), HH - 1.0f);
            float x0f = floorf(wc), y0f = floorf(hc);
            int x0 = (int)x0f, y0 = (int)y0f;
            int x1 = (int)ceilf(wc), y1 = (int)ceilf(hc);
            float dx = wc - x0f, dy = hc - y0f;
            s += (1 - dx) * (1 - dy) * fb[y0 * WW + x0] + dx * (1 - dy) * fb[y0 * WW + x1]
               + (1 - dx) * dy * fb[y1 * WW + x0] + dx * dy * fb[y1 * WW + x1];
            cnt++;
        }
    }
    out[(((size_t)n * CC + c) * POOLED + ph) * POOLED + pw] =
        cnt > 0 ? s / (float)cnt : 0.0f;
}

extern "C" void kernel_launch(void* const* d_in, const int* in_sizes, int n_in,
                              void* d_out, int out_size, void* d_ws, size_t ws_size,
                              hipStream_t stream) {
    const float* data   = (const float*)d_in[0];
    const float* rois   = (const float*)d_in[1];
    const float* offset = (const float*)d_in[2];
    float* out = (float*)d_out;
    int N = in_sizes[1] / 5;

    size_t feat_bytes  = (size_t)BB * CC * HH * WW * sizeof(float);
    size_t stage_bytes = (size_t)N * NBIN * CC * sizeof(float);
    int nbins = N * NBIN;

    if (ws_size >= feat_bytes + stage_bytes) {
        float* featT = (float*)d_ws;
        float* stage = (float*)((char*)d_ws + feat_bytes);
        dim3 tgrid(HH * WW / 32, CC / 32, BB);
        hipLaunchKernelGGL(transpose_chw_hwc, tgrid, dim3(32, 8), 0, stream,
                           data, featT);
        int nblk = (nbins + BPB - 1) / BPB;
        hipLaunchKernelGGL(dpsroi_pool3, dim3(nblk), dim3(256), 0, stream,
                           featT, rois, offset, stage, nbins);
        hipLaunchKernelGGL(relayout, dim3(N), dim3(256), 0, stream, stage, out);
    } else {
        hipLaunchKernelGGL(dpsroi_fallback, dim3(nbins), dim3(CC), 0, stream,
                           data, rois, offset, out, N);
    }
}

// Round 4
// 47.049 us; speedup vs baseline: 1.5539x; 1.1228x over previous
//
#include <hip/hip_runtime.h>
#include <hip/hip_bf16.h>

#define SPATIAL_SCALE 0.0625f
#define POOLED 7
#define NBIN 49
#define PARTS 7
#define SAMPLES 4
#define NSAMP 16
#define TRANS_STD 0.1f

#define BB 2
#define CC 128
#define HH 128
#define WW 128
#define HWC (HH * WW * CC)

#define WPB 4        // bins (waves) per block
#define WIN 5        // max window extent per axis (3*sub_w <= 2.91)
#define MAXP 28      // 25 cells + up to 3 padding entries

// ---------------- transpose (B,C,H,W) -> (B,H,W,C), 64x64 tiles ----------------
__global__ __launch_bounds__(256) void transpose_chw_hwc(
        const float* __restrict__ in, float* __restrict__ out) {
    __shared__ float tile[64][65];
    const int HW = HH * WW;
    int b  = blockIdx.z;
    size_t base = (size_t)b * CC * HW;
    int p0 = blockIdx.x * 64;   // position tile origin
    int c0 = blockIdx.y * 64;   // channel tile origin
    int tx = threadIdx.x & 63;
    int ty = threadIdx.x >> 6;  // 0..3
    #pragma unroll
    for (int i = ty; i < 64; i += 4) {
        tile[i][tx] = in[base + (size_t)(c0 + i) * HW + (p0 + tx)];
    }
    __syncthreads();
    #pragma unroll
    for (int i = ty; i < 64; i += 4) {
        out[base + (size_t)(p0 + i) * CC + (c0 + tx)] = tile[tx][i];
    }
}

// ---------------- dedup deformable PS-ROI pooling, one bin per wave ----------------
__global__ __launch_bounds__(256) void dpsroi_pool4(
        const float* __restrict__ feat,     // (B,H,W,C)
        const float* __restrict__ rois,
        const float* __restrict__ offset,
        float* __restrict__ stage,          // (nbins, C)
        int nbins) {
    __shared__ float s_w[WPB][WIN * WIN];
    __shared__ int2  s_ow[WPB][MAXP];       // {pixel*CC, bitcast weight}

    int tid  = threadIdx.x;
    int wv   = tid >> 6;
    int lane = tid & 63;
    int bing = blockIdx.x * WPB + wv;
    int binc = (bing < nbins) ? bing : (nbins - 1);

    int pw = binc % POOLED;
    int ph = (binc / POOLED) % POOLED;
    int n  = binc / NBIN;

    // ---- uniform per-bin geometry (all 64 lanes, wave-uniform) ----
    float R0 = rois[n * 5 + 0];
    float R1 = rois[n * 5 + 1];
    float R2 = rois[n * 5 + 2];
    float R3 = rois[n * 5 + 3];
    float R4 = rois[n * 5 + 4];
    int b = (int)R0;
    float roi_sw = rintf(R1) * SPATIAL_SCALE - 0.5f;
    float roi_sh = rintf(R2) * SPATIAL_SCALE - 0.5f;
    float roi_ew = rintf(R3 + 1.0f) * SPATIAL_SCALE - 0.5f;
    float roi_eh = rintf(R4 + 1.0f) * SPATIAL_SCALE - 0.5f;
    float roi_w = fmaxf(roi_ew - roi_sw, 0.1f);
    float roi_h = fmaxf(roi_eh - roi_sh, 0.1f);
    float bin_w = roi_w * (1.0f / POOLED);
    float bin_h = roi_h * (1.0f / POOLED);
    float sub_w = bin_w * (1.0f / SAMPLES);
    float sub_h = bin_h * (1.0f / SAMPLES);
    float tx = offset[((n * 2 + 0) * PARTS + ph) * PARTS + pw] * TRANS_STD;
    float ty = offset[((n * 2 + 1) * PARTS + ph) * PARTS + pw] * TRANS_STD;
    float wstart = (float)pw * bin_w + roi_sw + tx * roi_w;
    float hstart = (float)ph * bin_h + roi_sh + ty * roi_h;

    // window bounds (same FP exprs as extreme samples -> corners stay inside)
    float wlo = fminf(fmaxf(wstart, 0.0f), (float)WW - 1.0f);
    float whi = fminf(fmaxf(wstart + 3.0f * sub_w, 0.0f), (float)WW - 1.0f);
    float hlo = fminf(fmaxf(hstart, 0.0f), (float)HH - 1.0f);
    float hhi = fminf(fmaxf(hstart + 3.0f * sub_h, 0.0f), (float)HH - 1.0f);
    int c0 = (int)floorf(wlo);
    int r0 = (int)floorf(hlo);

    if (lane < WIN * WIN) s_w[wv][lane] = 0.0f;
    __syncthreads();

    // ---- per-sample weight accumulation (lanes 0..15) ----
    if (lane < NSAMP) {
        int iy = lane >> 2;
        int ix = lane & 3;
        float h = hstart + (float)iy * sub_h;
        float w = wstart + (float)ix * sub_w;
        bool valid = (w >= -0.5f) & (w <= (float)WW - 0.5f) &
                     (h >= -0.5f) & (h <= (float)HH - 0.5f);
        unsigned long long bal = __ballot(valid);
        int cnt = __popcll(bal);
        float sc = (cnt > 0) ? 1.0f / (float)cnt : 0.0f;
        if (valid) {
            float wc = fminf(fmaxf(w, 0.0f), (float)WW - 1.0f);
            float hc = fminf(fmaxf(h, 0.0f), (float)HH - 1.0f);
            float x0f = floorf(wc);
            float y0f = floorf(hc);
            int x0 = (int)x0f - c0;
            int y0 = (int)y0f - r0;
            int x1 = (int)ceilf(wc) - c0;
            int y1 = (int)ceilf(hc) - r0;
            float dx = wc - x0f;
            float dy = hc - y0f;
            atomicAdd(&s_w[wv][y0 * WIN + x0], (1.0f - dx) * (1.0f - dy) * sc);
            atomicAdd(&s_w[wv][y0 * WIN + x1], dx * (1.0f - dy) * sc);
            atomicAdd(&s_w[wv][y1 * WIN + x0], (1.0f - dx) * dy * sc);
            atomicAdd(&s_w[wv][y1 * WIN + x1], dx * dy * sc);
        }
    }
    __syncthreads();

    // ---- compact nonzero cells into padded (offset, weight) list ----
    float wg = (lane < WIN * WIN) ? s_w[wv][lane] : 0.0f;
    bool nz = (wg != 0.0f);
    unsigned long long bal2 = __ballot(nz);
    int cnt2 = __popcll(bal2);
    if (nz) {
        int pos = __popcll(bal2 & ((1ull << lane) - 1ull));
        int r  = lane / WIN;
        int cL = lane - r * WIN;
        int pix = (r0 + r) * WW + (c0 + cL);
        s_ow[wv][pos] = make_int2(pix * CC, __float_as_int(wg));
    }
    int P = (cnt2 + 3) & ~3;
    if (lane >= WIN * WIN && lane < WIN * WIN + 3) {
        int k = lane - WIN * WIN;
        if (cnt2 + k < P) s_ow[wv][cnt2 + k] = make_int2(0, 0);
    }
    __syncthreads();

    // ---- branch-free gather: 4 pixels per iteration, float2 = 2 channels/lane ----
    const float* fb = feat + (size_t)b * HWC + 2 * lane;
    float ax = 0.0f, ay = 0.0f;
    for (int i = 0; i < P; i += 4) {
        int2 e0 = s_ow[wv][i + 0];
        int2 e1 = s_ow[wv][i + 1];
        int2 e2 = s_ow[wv][i + 2];
        int2 e3 = s_ow[wv][i + 3];
        float2 v0 = *(const float2*)(fb + e0.x);
        float2 v1 = *(const float2*)(fb + e1.x);
        float2 v2 = *(const float2*)(fb + e2.x);
        float2 v3 = *(const float2*)(fb + e3.x);
        float w0 = __int_as_float(e0.y);
        float w1 = __int_as_float(e1.y);
        float w2 = __int_as_float(e2.y);
        float w3 = __int_as_float(e3.y);
        ax += w0 * v0.x; ay += w0 * v0.y;
        ax += w1 * v1.x; ay += w1 * v1.y;
        ax += w2 * v2.x; ay += w2 * v2.y;
        ax += w3 * v3.x; ay += w3 * v3.y;
    }
    if (bing < nbins) {
        float2 o; o.x = ax; o.y = ay;
        *(float2*)(stage + (size_t)bing * CC + 2 * lane) = o;
    }
}

// ---------------- relayout (N, bin, C) -> (N, C, bin) ----------------
#define LPAD 51
__global__ __launch_bounds__(256) void relayout(const float* __restrict__ ws,
                                                float* __restrict__ out) {
    __shared__ float t[CC * LPAD];
    int n = blockIdx.x;
    const float* src = ws + (size_t)n * CC * NBIN;
    for (int i = threadIdx.x; i < CC * NBIN; i += 256) {
        int c = i & (CC - 1);
        int bin = i >> 7;
        t[c * LPAD + bin] = src[i];
    }
    __syncthreads();
    float* dst = out + (size_t)n * CC * NBIN;
    for (int j = threadIdx.x; j < CC * NBIN; j += 256) {
        int c = j / NBIN;
        int bin = j - c * NBIN;
        dst[j] = t[c * LPAD + bin];
    }
}

// ---------------- fallback (no workspace): direct CHW ----------------
__global__ __launch_bounds__(128) void dpsroi_fallback(
        const float* __restrict__ feat,
        const float* __restrict__ rois,
        const float* __restrict__ offset,
        float* __restrict__ out, int N) {
    int bin = blockIdx.x;
    int pw = bin % POOLED;
    int ph = (bin / POOLED) % POOLED;
    int n  = bin / NBIN;
    int c  = threadIdx.x;
    float R1 = rois[n * 5 + 1], R2 = rois[n * 5 + 2];
    float R3 = rois[n * 5 + 3], R4 = rois[n * 5 + 4];
    int b = (int)rois[n * 5 + 0];
    float roi_sw = rintf(R1) * SPATIAL_SCALE - 0.5f;
    float roi_sh = rintf(R2) * SPATIAL_SCALE - 0.5f;
    float roi_ew = rintf(R3 + 1.0f) * SPATIAL_SCALE - 0.5f;
    float roi_eh = rintf(R4 + 1.0f) * SPATIAL_SCALE - 0.5f;
    float roi_w = fmaxf(roi_ew - roi_sw, 0.1f);
    float roi_h = fmaxf(roi_eh - roi_sh, 0.1f);
    float bin_w = roi_w / POOLED, bin_h = roi_h / POOLED;
    float sub_w = bin_w / SAMPLES, sub_h = bin_h / SAMPLES;
    float tx = offset[((n * 2 + 0) * PARTS + ph) * PARTS + pw] * TRANS_STD;
    float ty = offset[((n * 2 + 1) * PARTS + ph) * PARTS + pw] * TRANS_STD;
    float wstart = (float)pw * bin_w + roi_sw + tx * roi_w;
    float hstart = (float)ph * bin_h + roi_sh + ty * roi_h;
    const float* fb = feat + ((size_t)b * CC + c) * HH * WW;
    float s = 0.0f; int cnt = 0;
    for (int iy = 0; iy < SAMPLES; ++iy) {
        float h = hstart + iy * sub_h;
        for (int ix = 0; ix < SAMPLES; ++ix) {
            float w = wstart + ix * sub_w;
            if (!((w >= -0.5f) & (w <= WW - 0.5f) & (h >= -0.5f) & (h <= HH - 0.5f)))
                continue;
            float wc = fminf(fmaxf(w, 0.0f), WW - 1.0f);
            float hc = fminf(fmaxf(h, 0.0f), HH - 1.0f);
            float x0f = floorf(wc), y0f = floorf(hc);
            int x0 = (int)x0f, y0 = (int)y0f;
            int x1 = (int)ceilf(wc), y1 = (int)ceilf(hc);
            float dx = wc - x0f, dy = hc - y0f;
            s += (1 - dx) * (1 - dy) * fb[y0 * WW + x0] + dx * (1 - dy) * fb[y0 * WW + x1]
               + (1 - dx) * dy * fb[y1 * WW + x0] + dx * dy * fb[y1 * WW + x1];
            cnt++;
        }
    }
    out[(((size_t)n * CC + c) * POOLED + ph) * POOLED + pw] =
        cnt > 0 ? s / (float)cnt : 0.0f;
}

extern "C" void kernel_launch(void* const* d_in, const int* in_sizes, int n_in,
                              void* d_out, int out_size, void* d_ws, size_t ws_size,
                              hipStream_t stream) {
    const float* data   = (const float*)d_in[0];
    const float* rois   = (const float*)d_in[1];
    const float* offset = (const float*)d_in[2];
    float* out = (float*)d_out;
    int N = in_sizes[1] / 5;

    size_t feat_bytes  = (size_t)BB * CC * HH * WW * sizeof(float);
    size_t stage_bytes = (size_t)N * NBIN * CC * sizeof(float);
    int nbins = N * NBIN;

    if (ws_size >= feat_bytes + stage_bytes) {
        float* featT = (float*)d_ws;
        float* stage = (float*)((char*)d_ws + feat_bytes);
        dim3 tgrid(HH * WW / 64, CC / 64, BB);
        hipLaunchKernelGGL(transpose_chw_hwc, tgrid, dim3(256), 0, stream,
                           data, featT);
        int nblk = (nbins + WPB - 1) / WPB;
        hipLaunchKernelGGL(dpsroi_pool4, dim3(nblk), dim3(256), 0, stream,
                           featT, rois, offset, stage, nbins);
        hipLaunchKernelGGL(relayout, dim3(N), dim3(256), 0, stream, stage, out);
    } else {
        hipLaunchKernelGGL(dpsroi_fallback, dim3(nbins), dim3(CC), 0, stream,
                           data, rois, offset, out, N);
    }
}